// Round 2
// baseline (443.218 us; speedup 1.0000x reference)
//
#include <hip/hip_runtime.h>
#include <hip/hip_bf16.h>

// Problem constants (match reference setup_inputs / hyperparams)
constexpr int B  = 4;
constexpr int H  = 544;
constexpr int W  = 960;
constexpr int H2 = 272;   // half-res
constexpr int W2 = 480;
constexpr int NH = B * H2 * W2;     // 522240
constexpr int NF = B * H * W;       // 2088960

// pixel kernel tiling: 32x8 outputs per block, halo 1 -> 34x10 staged
constexpr int TPW = 32, TPH = 8;
constexpr int SW = TPW + 2, SH = TPH + 2;      // 34 x 10
constexpr int NSTAGE = SW * SH;                // 340
constexpr int GX = W / TPW;                    // 30
constexpr int GY = H / TPH;                    // 68
constexpr int NBLK  = GX * GY * B;             // 8160 (k_pix blocks)
constexpr int NBLK2 = (NH + 255) / 256;        // 2040 (k_sgm blocks)

__device__ inline float waveSum(float v) {
  #pragma unroll
  for (int off = 32; off > 0; off >>= 1) v += __shfl_down(v, off, 64);
  return v;
}

// ------- fused pixel kernel: gt + photometric + smoothness + lg/rg downsample -------
__global__ __launch_bounds__(256) void k_pix(const float* __restrict__ pred,
                                             const float* __restrict__ gt,
                                             const float* __restrict__ conf,
                                             const float* __restrict__ occ,
                                             const float* __restrict__ left,
                                             const float* __restrict__ right,
                                             float* __restrict__ lg,
                                             float* __restrict__ rg,
                                             float* __restrict__ partialsA) {
  const int bx = blockIdx.x % GX;
  const int by = (blockIdx.x / GX) % GY;
  const int b  = blockIdx.x / (GX * GY);
  const int x0 = bx * TPW, y0 = by * TPH;
  const int tid = threadIdx.x;

  const float* dispb = pred + (size_t)b * H * W;
  const float* lb = left  + (size_t)b * 3 * H * W;
  const float* rb = right + (size_t)b * 3 * H * W;

  __shared__ float4 L4s[NSTAGE];   // (lv0, lv1, lv2, disp); zeros if OOB
  __shared__ float4 W4s[NSTAGE];   // (wv0, wv1, wv2, 0);    zeros if OOB

  for (int e = tid; e < NSTAGE; e += 256) {
    int r = e / SW, c = e % SW;
    int yy = y0 - 1 + r, xx = x0 - 1 + c;
    float4 l4 = make_float4(0.f, 0.f, 0.f, 0.f);
    float4 w4 = make_float4(0.f, 0.f, 0.f, 0.f);
    if (yy >= 0 && yy < H && xx >= 0 && xx < W) {
      float dv = dispb[yy * W + xx];
      float xsv = (float)xx - dv;
      float xc = fminf(fmaxf(xsv, 0.f), (float)(W - 1));
      float x0f = floorf(xc);
      float w = xc - x0f;
      int x0i = (int)x0f;
      int x1i = min(x0i + 1, W - 1);
      const float* l0 = lb + (size_t)yy * W;
      const float* r0 = rb + (size_t)yy * W;
      l4.x = l0[xx];
      l4.y = l0[(size_t)H * W + xx];
      l4.z = l0[2 * (size_t)H * W + xx];
      l4.w = dv;
      w4.x = r0[x0i] * (1.f - w) + r0[x1i] * w;
      w4.y = r0[(size_t)H * W + x0i] * (1.f - w) + r0[(size_t)H * W + x1i] * w;
      w4.z = r0[2 * (size_t)H * W + x0i] * (1.f - w) + r0[2 * (size_t)H * W + x1i] * w;
    }
    L4s[e] = l4; W4s[e] = w4;
  }
  __syncthreads();

  // ---- lg/rg emission (threads 0..63): 16x4 half-res pixels of this tile ----
  if (tid < 64) {
    int hx = tid & 15, hy = tid >> 4;
    int y2g = (y0 >> 1) + hy, x2g = (x0 >> 1) + hx;
    int i00 = (2 * hy + 1) * SW + (2 * hx + 1);
    float4 a00 = L4s[i00], a01 = L4s[i00 + 1], a10 = L4s[i00 + SW], a11 = L4s[i00 + SW + 1];
    float sl = 0.f;
    sl += a00.x + a01.x + a10.x + a11.x;
    sl += a00.y + a01.y + a10.y + a11.y;
    sl += a00.z + a01.z + a10.z + a11.z;
    float sr = 0.f;
    int yy2 = y0 + 2 * hy, xx2 = x0 + 2 * hx;
    #pragma unroll
    for (int c = 0; c < 3; c++) {
      const float* rp = rb + (size_t)(c * H + yy2) * W + xx2;
      sr += rp[0] + rp[1] + rp[W] + rp[W + 1];
    }
    size_t ho = (size_t)b * (H2 * W2) + (size_t)y2g * W2 + x2g;
    lg[ho] = sl * (1.f / 12.f);
    rg[ho] = sr * (1.f / 12.f);
  }

  float v[6];
  #pragma unroll
  for (int s = 0; s < 6; s++) v[s] = 0.f;

  {
    const int tx = tid & 31, ty = tid >> 5;
    const int x = x0 + tx, y = y0 + ty;
    const size_t gidx = (size_t)b * H * W + (size_t)y * W + x;
    const int ci = (ty + 1) * SW + (tx + 1);

    float sl[3] = {0,0,0}, sw[3] = {0,0,0}, sl2[3] = {0,0,0},
          sw2[3] = {0,0,0}, slw[3] = {0,0,0};
    float4 cl4, cw4, rl4, dl4;
    #pragma unroll
    for (int dy = -1; dy <= 1; dy++) {
      #pragma unroll
      for (int dx = -1; dx <= 1; dx++) {
        int ni = ci + dy * SW + dx;
        float4 a = L4s[ni];
        float4 wv = W4s[ni];
        sl[0] += a.x;  sl2[0] += a.x * a.x;  sw[0] += wv.x;  sw2[0] += wv.x * wv.x;  slw[0] += a.x * wv.x;
        sl[1] += a.y;  sl2[1] += a.y * a.y;  sw[1] += wv.y;  sw2[1] += wv.y * wv.y;  slw[1] += a.y * wv.y;
        sl[2] += a.z;  sl2[2] += a.z * a.z;  sw[2] += wv.z;  sw2[2] += wv.z * wv.z;  slw[2] += a.z * wv.z;
        if (dy == 0 && dx == 0) { cl4 = a; cw4 = wv; }
        if (dy == 0 && dx == 1) rl4 = a;
        if (dy == 1 && dx == 0) dl4 = a;
      }
    }
    float ds = cl4.w;

    // ---- gt anchor ----
    {
      float g = gt[gidx];
      float trust = (g > 2.0f) ? conf[gidx] * occ[gidx] : 0.f;
      v[0] = trust * fabsf(ds - g);
      v[1] = trust;
    }

    // ---- photometric ----
    {
      float xs = (float)x - ds;
      bool valid = (xs > 0.f) && (xs < (float)(W - 1));
      float cl[3] = {cl4.x, cl4.y, cl4.z};
      float cw[3] = {cw4.x, cw4.y, cw4.z};
      float ssm = 0.f, l1m = 0.f;
      #pragma unroll
      for (int c = 0; c < 3; c++) {
        float mx = sl[c] * (1.f / 9.f), my = sw[c] * (1.f / 9.f);
        float sx = fmaxf(sl2[c] * (1.f / 9.f) - mx * mx, 0.f);
        float sy = fmaxf(sw2[c] * (1.f / 9.f) - my * my, 0.f);
        float sxy = slw[c] * (1.f / 9.f) - mx * my;
        float n  = (2.f * mx * my + 1e-4f) * (2.f * sxy + 9e-4f);
        float dd = (mx * mx + my * my + 1e-4f) * (sx + sy + 9e-4f);
        float ss = (1.f - n / dd) * 0.5f;
        ss = fminf(fmaxf(ss, 0.f), 1.f);
        ssm += ss;
        l1m += fabsf(cl[c] - cw[c]);
      }
      ssm *= (1.f / 3.f); l1m *= (1.f / 3.f);
      float err = 0.85f * ssm + 0.15f * l1m;
      if (valid) { v[2] = err; v[3] = 1.f; }
    }

    // ---- smoothness ----
    if (x < W - 1) {
      float ddx = fabsf(rl4.w - ds);
      float idx = fabsf(rl4.x - cl4.x) + fabsf(rl4.y - cl4.y) + fabsf(rl4.z - cl4.z);
      v[4] = ddx * __expf(-idx * (1.f / 3.f));
    }
    if (y < H - 1) {
      float ddy = fabsf(dl4.w - ds);
      float idy = fabsf(dl4.x - cl4.x) + fabsf(dl4.y - cl4.y) + fabsf(dl4.z - cl4.z);
      v[5] = ddy * __expf(-idy * (1.f / 3.f));
    }
  }

  __shared__ float sm[4][6];
  int wave = threadIdx.x >> 6, lane = threadIdx.x & 63;
  #pragma unroll
  for (int s = 0; s < 6; s++) {
    float r = waveSum(v[s]);
    if (lane == 0) sm[wave][s] = r;
  }
  __syncthreads();
  if (threadIdx.x < 6) {
    float t = sm[0][threadIdx.x] + sm[1][threadIdx.x] +
              sm[2][threadIdx.x] + sm[3][threadIdx.x];
    partialsA[(size_t)threadIdx.x * NBLK + blockIdx.x] = t;
  }
}

// ---------------- fused NCC disparity search, 4 d-groups (R11) --------------------
// grp g covers 12 d's: g0 [-24..-13], g1 [-12..-1], g2 [1..12], g3 [13..24].
// R11 = R10's single-d pipeline with the scratch-spill bug fixed.
// R10 post-mortem: chpass was a lambda taking a RUNTIME j; rgv[j+k] was
// runtime-indexed at SROA time -> lgc[18]+rgv[29] demoted to scratch
// (WRITE_SIZE 16 MB -> 497 MB, 79 -> 258 us). Rule #20: every thread-local
// array index must be a compile-time literal. Fix: CHPASS(J,...) macro with
// literal J, dispatched via switch(it) with literal cases (folds away under
// full unroll; mere branches otherwise — either way no runtime-indexed array
// exists in the program).
// Structure (unchanged from R10, which was numerically correct):
//   * rgv[29] preloaded ONCE via b128 (RGs rows padded 85->88, 16B-aligned).
//   * single-d iterations, CH ping-pong inside the SAME 3328-float POOL.
//   * one barrier per d; each region interleaves vertical(it) [LDS-read
//     chains] with CH(it+1) [pure register FMAs + 2 b128 writes].
// LDS 8848 floats = 35392 B -> 4 blocks/CU:
//   @0:    LGs 26x74 (dead after LH) overlaid by RMS float2[16][76] (2432)
//   @2432: RGs 26x88 (85 logical cols, padded) | @4720: POOL 3328 (LH pair /
//          VR pair / CH ping-pong, stride 64)
//   @8048: P1 16x25 | @8448: P2
constexpr int RGST = 88;   // padded RGs row stride (352 B, 16B-aligned rows)

// CH pass for d = dmin + J: pure register VALU from lgc x rgv, J LITERAL.
#define CHPASS(J, dstp) do {                                                   \
    if (hr < 26) {                                                             \
      float ca_[8];                                                            \
      float s_ = 0.f;                                                          \
      _Pragma("unroll")                                                        \
      for (int k_ = 0; k_ < 11; k_++) s_ += lgc[k_] * rgv[(J) + k_];           \
      ca_[0] = s_;                                                             \
      _Pragma("unroll")                                                        \
      for (int j_ = 1; j_ < 8; j_++) {                                         \
        s_ += lgc[j_ + 10] * rgv[(J) + j_ + 10] - lgc[j_ - 1] * rgv[(J) + j_ - 1]; \
        ca_[j_] = s_;                                                          \
      }                                                                        \
      *(float4*)&(dstp)[hr * 64 + 8 * hg]     = make_float4(ca_[0], ca_[1], ca_[2], ca_[3]); \
      *(float4*)&(dstp)[hr * 64 + 8 * hg + 4] = make_float4(ca_[4], ca_[5], ca_[6], ca_[7]); \
    }                                                                          \
  } while (0)

__global__ __launch_bounds__(256, 4) void k_ncc(const float* __restrict__ lg,
                                                const float* __restrict__ rg,
                                                float* __restrict__ bcA,
                                                float* __restrict__ bdA) {
  const int z = blockIdx.z;
  const int b = z >> 2, grp = z & 3;
  const int dmin = (grp == 0) ? -24 : ((grp == 1) ? -12 : ((grp == 2) ? 1 : 13));
  const int x0 = blockIdx.x * 64;
  const int y0 = blockIdx.y * 16;
  const int tid = threadIdx.x;

  __shared__ __align__(16) float SM[8848];
  float* LGs = SM;             // 26 x 74
  float* RMS = SM;             // float2[16][76] row-major (overlays dead LGs)
  float* RGs = SM + 2432;      // 26 x 88 (logical 85 cols)
  float* POOL = SM + 4720;     // 3328
  float* P1 = SM + 8048;       // 16 x 25
  float* P2 = SM + 8448;

  const float* lgb = lg + (size_t)b * (H2 * W2);
  const float* rgb = rg + (size_t)b * (H2 * W2);

  for (int e = tid; e < 26 * 74; e += 256) {
    int r = e / 74, c = e % 74;
    int gy = y0 - 5 + r, gxx = x0 - 5 + c;
    LGs[e] = (gy >= 0 && gy < H2 && gxx >= 0 && gxx < W2) ? lgb[gy * W2 + gxx] : 0.f;
  }
  const int col0RG = x0 - 5 + dmin;
  for (int e = tid; e < 26 * 85; e += 256) {
    int r = e / 85, c = e % 85;
    int gy = y0 - 5 + r, gxx = col0RG + c;
    RGs[r * RGST + c] = (gy >= 0 && gy < H2 && gxx >= 0 && gxx < W2) ? rgb[gy * W2 + gxx] : 0.f;
  }
  __syncthreads();

  // ---- LH pass (horizontal 11-sums of lg, lg^2) + lgc/rgv register caches ----
  const int hg = tid & 7, hr = tid >> 3;
  float lgc[18];
  float rgv[29];
  float* LH1 = POOL;           // 26 x 64
  float* LH2 = POOL + 1664;
  if (hr < 26) {
    #pragma unroll
    for (int k = 0; k < 18; k++) lgc[k] = LGs[hr * 74 + 8 * hg + k];
    // rgv preload: the only RGs data this thread ever needs across all 12 d's
    const float* rp = &RGs[hr * RGST + 8 * hg];
    #pragma unroll
    for (int m = 0; m < 7; m++) {
      float4 q = *(const float4*)(rp + 4 * m);
      rgv[4 * m] = q.x; rgv[4 * m + 1] = q.y; rgv[4 * m + 2] = q.z; rgv[4 * m + 3] = q.w;
    }
    rgv[28] = rp[28];
    float w1[8], w2[8];
    float s1 = 0.f, s2 = 0.f;
    #pragma unroll
    for (int k = 0; k < 11; k++) { s1 += lgc[k]; s2 += lgc[k] * lgc[k]; }
    w1[0] = s1; w2[0] = s2;
    #pragma unroll
    for (int j = 1; j < 8; j++) {
      s1 += lgc[j + 10] - lgc[j - 1];
      s2 += lgc[j + 10] * lgc[j + 10] - lgc[j - 1] * lgc[j - 1];
      w1[j] = s1; w2[j] = s2;
    }
    *(float4*)&LH1[hr * 64 + 8 * hg]     = make_float4(w1[0], w1[1], w1[2], w1[3]);
    *(float4*)&LH1[hr * 64 + 8 * hg + 4] = make_float4(w1[4], w1[5], w1[6], w1[7]);
    *(float4*)&LH2[hr * 64 + 8 * hg]     = make_float4(w2[0], w2[1], w2[2], w2[3]);
    *(float4*)&LH2[hr * 64 + 8 * hg + 4] = make_float4(w2[4], w2[5], w2[6], w2[7]);
  }
  // ---- border column sums (head: global cols 0..23; tail: 456..479) ----
  const bool headT = (grp >= 2) && (x0 == 0);
  const bool tailT = (grp < 2) && (x0 == 448);
  if (headT || tailT) {
    int gcol0 = headT ? 0 : 456;
    for (int e = tid; e < 16 * 24; e += 256) {
      int y = e / 24, i = e % 24;
      int lc = gcol0 + i - col0RG;
      float v1 = 0.f, v2 = 0.f;
      if (lc >= 0 && lc < 85) {
        #pragma unroll
        for (int dy = 0; dy < 11; dy++) {
          float v = RGs[(y + dy) * RGST + lc];
          v1 += v; v2 += v * v;
        }
      }
      P1[y * 25 + i + 1] = v1;
      P2[y * 25 + i + 1] = v2;
    }
  }
  __syncthreads();

  if ((headT || tailT) && tid < 16) {
    int y = tid;
    float s1 = 0.f, s2 = 0.f;
    P1[y * 25] = 0.f; P2[y * 25] = 0.f;
    for (int k = 0; k < 24; k++) {
      s1 += P1[y * 25 + k + 1]; P1[y * 25 + k + 1] = s1;
      s2 += P2[y * 25 + k + 1]; P2[y * 25 + k + 1] = s2;
    }
  }
  const int vx = tid & 63;
  const int vys = (tid >> 6) * 4;
  float lmS[4], lsS[4];   // 121-scaled left mean / std
  {
    float s1 = 0.f, s2 = 0.f;
    #pragma unroll
    for (int dy = 0; dy < 11; dy++) { s1 += LH1[(vys + dy) * 64 + vx]; s2 += LH2[(vys + dy) * 64 + vx]; }
    #pragma unroll
    for (int k = 0; k < 4; k++) {
      if (k) {
        s1 += LH1[(vys + k + 10) * 64 + vx] - LH1[(vys + k - 1) * 64 + vx];
        s2 += LH2[(vys + k + 10) * 64 + vx] - LH2[(vys + k - 1) * 64 + vx];
      }
      float m = s1 * (1.f / 121.f);
      float s = sqrtf(fmaxf(s2 * (1.f / 121.f) - m * m, 1e-8f));
      lmS[k] = m * 121.f;
      lsS[k] = s * 121.f;
    }
  }
  __syncthreads();

  // ---- VR pass: vertical 11-sums of rg, rg^2 (POOL, overwrites LH) ----
  float* VR1 = POOL;           // 16 x 85
  float* VR2 = POOL + 1360;
  if (tid < 170) {
    int c = tid % 85;
    int rr0 = (tid / 85) * 8;
    float s1 = 0.f, s2 = 0.f;
    #pragma unroll
    for (int dy = 0; dy < 11; dy++) {
      float v = RGs[(rr0 + dy) * RGST + c];
      s1 += v; s2 += v * v;
    }
    VR1[rr0 * 85 + c] = s1; VR2[rr0 * 85 + c] = s2;
    #pragma unroll
    for (int k = 1; k < 8; k++) {
      float vin  = RGs[(rr0 + k + 10) * RGST + c];
      float vout = RGs[(rr0 + k - 1) * RGST + c];
      s1 += vin - vout;
      s2 += vin * vin - vout * vout;
      VR1[(rr0 + k) * 85 + c] = s1; VR2[(rr0 + k) * 85 + c] = s2;
    }
  }
  __syncthreads();

  // ---- RV pass fused with moment transform -> RMS float2 (rm, rstd) ----
  {
    int r = tid >> 4, seg = tid & 15;
    int c0 = seg * 5;
    if (c0 < 75) {
      float s1 = 0.f, s2 = 0.f;
      #pragma unroll
      for (int m = 0; m < 11; m++) { s1 += VR1[r * 85 + c0 + m]; s2 += VR2[r * 85 + c0 + m]; }
      #pragma unroll
      for (int j = 0; j < 5; j++) {
        if (j) {
          s1 += VR1[r * 85 + c0 + j + 10] - VR1[r * 85 + c0 + j - 1];
          s2 += VR2[r * 85 + c0 + j + 10] - VR2[r * 85 + c0 + j - 1];
        }
        float rm = s1 * (1.f / 121.f);
        float rstd = sqrtf(fmaxf(s2 * (1.f / 121.f) - rm * rm, 1e-8f));
        *(float2*)&RMS[r * 152 + 2 * (c0 + j)] = make_float2(rm, rstd);
      }
    }
  }
  __syncthreads();

  // ---- d loop: 12 single-d iterations, CH ping-pong, 1 barrier each ----
  const int gx = x0 + vx;
  const bool headL = (grp >= 2) && (gx < 5);
  const bool tailL = (grp < 2) && (gx > 474);
  const bool edgeL = headL || tailL;
  float bnum[4], bden[4], bdd[4];
  #pragma unroll
  for (int k = 0; k < 4; k++) { bnum[k] = -1.f; bden[k] = 1.f; bdd[k] = 0.f; }

  // prologue: CH(0) into buffer 0 (POOL free: VR dead after RMS pass)
  CHPASS(0, POOL);
  __syncthreads();

  #pragma unroll
  for (int it = 0; it < 12; ++it) {
    float* CHr = POOL + ((it & 1) ? 1664 : 0);
    float* CHw = POOL + ((it & 1) ? 0 : 1664);
    // issue next d's CH (register FMAs + 2 b128 writes) to overlap with the
    // vertical read chains below — disjoint ping-pong buffer, no hazard.
    // switch with LITERAL cases: folds away under full unroll; never creates
    // a runtime-indexed access into rgv (rule #20).
    switch (it) {
      case 0:  CHPASS(1,  CHw); break;
      case 1:  CHPASS(2,  CHw); break;
      case 2:  CHPASS(3,  CHw); break;
      case 3:  CHPASS(4,  CHw); break;
      case 4:  CHPASS(5,  CHw); break;
      case 5:  CHPASS(6,  CHw); break;
      case 6:  CHPASS(7,  CHw); break;
      case 7:  CHPASS(8,  CHw); break;
      case 8:  CHPASS(9,  CHw); break;
      case 9:  CHPASS(10, CHw); break;
      case 10: CHPASS(11, CHw); break;
      default: break;   // it == 11: no prefetch
    }
    const int d = dmin + it;
    {
      float a = 0.f;
      #pragma unroll
      for (int dy = 0; dy < 11; dy++) a += CHr[(vys + dy) * 64 + vx];
      #pragma unroll
      for (int k = 0; k < 4; k++) {
        if (k) a += CHr[(vys + k + 10) * 64 + vx] - CHr[(vys + k - 1) * 64 + vx];
        float cs = a;                    // raw 121-sum of lg*rg_shift
        int rvi = vx + it;
        float2 ms = *(const float2*)&RMS[(vys + k) * 152 + 2 * rvi];
        float rm = ms.x, rstd = ms.y;
        if (edgeL) {
          float rs = rm * 121.f;
          float r2 = (rstd * rstd + rm * rm) * 121.f;
          int a_, bI;
          if (headL) { a_ = max(gx - 5 + d, 0); bI = d; }
          else       { a_ = 24 + d; bI = min(gx + 5 + d, 479) - 455; }
          rs -= P1[(vys + k) * 25 + bI] - P1[(vys + k) * 25 + a_];
          r2 -= P2[(vys + k) * 25 + bI] - P2[(vys + k) * 25 + a_];
          rm = rs * (1.f / 121.f);
          rstd = sqrtf(fmaxf(r2 * (1.f / 121.f) - rm * rm, 1e-8f));
        }
        float num = __builtin_fmaf(-lmS[k], rm, cs);
        float den = __builtin_fmaf(lsS[k], rstd, 1.21e-6f);
        if (num * bden[k] > bnum[k] * den) { bnum[k] = num; bden[k] = den; bdd[k] = (float)d; }
      }
    }
    if (it < 11) __syncthreads();
  }

  if (gx < W2) {
    float* bcp = bcA + (size_t)grp * NH + (size_t)b * (H2 * W2);
    float* bdp = bdA + (size_t)grp * NH + (size_t)b * (H2 * W2);
    #pragma unroll
    for (int k = 0; k < 4; k++) {
      size_t o = (size_t)(y0 + vys + k) * W2 + gx;
      bcp[o] = bnum[k] / bden[k];
      bdp[o] = bdd[k];
    }
  }
}

// ------- sign/magnitude: merge 4 d-groups (ascending, strict >), 4 preds each -------
__global__ __launch_bounds__(256) void k_sgm(const float* __restrict__ pred,
                                             const float* __restrict__ bcA,
                                             const float* __restrict__ bdA,
                                             float* __restrict__ partialsB) {
  int tid = blockIdx.x * 256 + threadIdx.x;
  float v6 = 0.f, v7 = 0.f, v8 = 0.f;
  if (tid < NH) {
    int b = tid / (H2 * W2);
    int rem = tid % (H2 * W2);
    int y2 = rem / W2, x2 = rem % W2;
    float bcv = bcA[tid];
    float bdv = bdA[tid];
    #pragma unroll
    for (int g = 1; g < 4; g++) {
      float c = bcA[(size_t)g * NH + tid];
      if (c > bcv) { bcv = c; bdv = bdA[(size_t)g * NH + tid]; }
    }
    if (bcv > 0.3f) {
      float nd = bdv * 2.f;
      float sgn = (nd > 0.f) ? 1.f : ((nd < 0.f) ? -1.f : 0.f);
      const float* pb = pred + (size_t)b * H * W;
      #pragma unroll
      for (int dy = 0; dy < 2; dy++) {
        #pragma unroll
        for (int dx = 0; dx < 2; dx++) {
          float p = pb[(size_t)(2 * y2 + dy) * W + 2 * x2 + dx];
          v6 += fmaxf(-p * sgn, 0.f);
          v7 += bcv * fabsf(p - nd);
        }
      }
      v8 = 4.f;
    }
  }
  __shared__ float sm[4][3];
  int wave = threadIdx.x >> 6, lane = threadIdx.x & 63;
  float r;
  r = waveSum(v6); if (lane == 0) sm[wave][0] = r;
  r = waveSum(v7); if (lane == 0) sm[wave][1] = r;
  r = waveSum(v8); if (lane == 0) sm[wave][2] = r;
  __syncthreads();
  if (threadIdx.x < 3) {
    float t = sm[0][threadIdx.x] + sm[1][threadIdx.x] +
              sm[2][threadIdx.x] + sm[3][threadIdx.x];
    partialsB[(size_t)threadIdx.x * NBLK2 + blockIdx.x] = t;
  }
}

// ---------------- final reduction + scalar composition (1024 threads) ----------------
__global__ __launch_bounds__(1024) void k_final(const float* __restrict__ PA,
                                                const float* __restrict__ PB,
                                                float* __restrict__ out) {
  __shared__ float red[9][16];
  int lane = threadIdx.x & 63, wave = threadIdx.x >> 6;
  #pragma unroll
  for (int s = 0; s < 6; s++) {
    float l = 0.f;
    for (int i = threadIdx.x; i < NBLK; i += 1024) l += PA[(size_t)s * NBLK + i];
    l = waveSum(l);
    if (lane == 0) red[s][wave] = l;
  }
  #pragma unroll
  for (int s = 0; s < 3; s++) {
    float l = 0.f;
    for (int i = threadIdx.x; i < NBLK2; i += 1024) l += PB[(size_t)s * NBLK2 + i];
    l = waveSum(l);
    if (lane == 0) red[6 + s][wave] = l;
  }
  __syncthreads();
  if (threadIdx.x == 0) {
    float a[9];
    #pragma unroll
    for (int s = 0; s < 9; s++) {
      float t = 0.f;
      #pragma unroll
      for (int q = 0; q < 16; q++) t += red[s][q];
      a[s] = t;
    }
    float gtl = a[0] / fmaxf(a[1], 1.f);
    float ph  = a[2] / fmaxf(a[3], 1.f);
    float n   = fmaxf(a[8], 1.f);
    float smv = 0.3f * (a[6] / n) + 0.7f * (a[7] / n);
    float smo = a[4] * (1.f / ((float)B * H * (W - 1)))
              + a[5] * (1.f / ((float)B * (H - 1) * W));
    out[0] = gtl + ph + 0.5f * smv + 0.1f * smo;
  }
}

extern "C" void kernel_launch(void* const* d_in, const int* in_sizes, int n_in,
                              void* d_out, int out_size, void* d_ws, size_t ws_size,
                              hipStream_t stream) {
  const float* pred  = (const float*)d_in[0];
  const float* gt    = (const float*)d_in[1];
  const float* conf  = (const float*)d_in[2];
  const float* occ   = (const float*)d_in[3];
  const float* left  = (const float*)d_in[4];
  const float* right = (const float*)d_in[5];
  float* out = (float*)d_out;

  float* ws = (float*)d_ws;
  float* lg  = ws;
  float* rg  = ws + (size_t)NH;
  float* bcA = ws + 2 * (size_t)NH;                  // 4 * NH
  float* bdA = ws + 6 * (size_t)NH;                  // 4 * NH
  float* partialsA = ws + 10 * (size_t)NH;           // 6 * NBLK
  float* partialsB = partialsA + 6 * (size_t)NBLK;   // 3 * NBLK2

  k_pix<<<NBLK, 256, 0, stream>>>(pred, gt, conf, occ, left, right,
                                  lg, rg, partialsA);

  dim3 nccGrid(8, 17, 16);   // x-tiles, y-tiles, batch*4 d-groups
  k_ncc<<<nccGrid, 256, 0, stream>>>(lg, rg, bcA, bdA);

  k_sgm<<<NBLK2, 256, 0, stream>>>(pred, bcA, bdA, partialsB);

  k_final<<<1, 1024, 0, stream>>>(partialsA, partialsB, out);
}

// Round 3
// 244.090 us; speedup vs baseline: 1.8158x; 1.8158x over previous
//
#include <hip/hip_runtime.h>
#include <hip/hip_bf16.h>

// Problem constants (match reference setup_inputs / hyperparams)
constexpr int B  = 4;
constexpr int H  = 544;
constexpr int W  = 960;
constexpr int H2 = 272;   // half-res
constexpr int W2 = 480;
constexpr int NH = B * H2 * W2;     // 522240
constexpr int NF = B * H * W;       // 2088960

// pixel kernel tiling: 32x8 outputs per block, halo 1 -> 34x10 staged
constexpr int TPW = 32, TPH = 8;
constexpr int SW = TPW + 2, SH = TPH + 2;      // 34 x 10
constexpr int NSTAGE = SW * SH;                // 340
constexpr int GX = W / TPW;                    // 30
constexpr int GY = H / TPH;                    // 68
constexpr int NBLK  = GX * GY * B;             // 8160 (k_pix blocks)
constexpr int NBLK2 = (NH + 255) / 256;        // 2040 (k_sgm blocks)

__device__ inline float waveSum(float v) {
  #pragma unroll
  for (int off = 32; off > 0; off >>= 1) v += __shfl_down(v, off, 64);
  return v;
}

// ------- fused pixel kernel: gt + photometric + smoothness + lg/rg downsample -------
__global__ __launch_bounds__(256) void k_pix(const float* __restrict__ pred,
                                             const float* __restrict__ gt,
                                             const float* __restrict__ conf,
                                             const float* __restrict__ occ,
                                             const float* __restrict__ left,
                                             const float* __restrict__ right,
                                             float* __restrict__ lg,
                                             float* __restrict__ rg,
                                             float* __restrict__ partialsA) {
  const int bx = blockIdx.x % GX;
  const int by = (blockIdx.x / GX) % GY;
  const int b  = blockIdx.x / (GX * GY);
  const int x0 = bx * TPW, y0 = by * TPH;
  const int tid = threadIdx.x;

  const float* dispb = pred + (size_t)b * H * W;
  const float* lb = left  + (size_t)b * 3 * H * W;
  const float* rb = right + (size_t)b * 3 * H * W;

  __shared__ float4 L4s[NSTAGE];   // (lv0, lv1, lv2, disp); zeros if OOB
  __shared__ float4 W4s[NSTAGE];   // (wv0, wv1, wv2, 0);    zeros if OOB

  for (int e = tid; e < NSTAGE; e += 256) {
    int r = e / SW, c = e % SW;
    int yy = y0 - 1 + r, xx = x0 - 1 + c;
    float4 l4 = make_float4(0.f, 0.f, 0.f, 0.f);
    float4 w4 = make_float4(0.f, 0.f, 0.f, 0.f);
    if (yy >= 0 && yy < H && xx >= 0 && xx < W) {
      float dv = dispb[yy * W + xx];
      float xsv = (float)xx - dv;
      float xc = fminf(fmaxf(xsv, 0.f), (float)(W - 1));
      float x0f = floorf(xc);
      float w = xc - x0f;
      int x0i = (int)x0f;
      int x1i = min(x0i + 1, W - 1);
      const float* l0 = lb + (size_t)yy * W;
      const float* r0 = rb + (size_t)yy * W;
      l4.x = l0[xx];
      l4.y = l0[(size_t)H * W + xx];
      l4.z = l0[2 * (size_t)H * W + xx];
      l4.w = dv;
      w4.x = r0[x0i] * (1.f - w) + r0[x1i] * w;
      w4.y = r0[(size_t)H * W + x0i] * (1.f - w) + r0[(size_t)H * W + x1i] * w;
      w4.z = r0[2 * (size_t)H * W + x0i] * (1.f - w) + r0[2 * (size_t)H * W + x1i] * w;
    }
    L4s[e] = l4; W4s[e] = w4;
  }
  __syncthreads();

  // ---- lg/rg emission (threads 0..63): 16x4 half-res pixels of this tile ----
  if (tid < 64) {
    int hx = tid & 15, hy = tid >> 4;
    int y2g = (y0 >> 1) + hy, x2g = (x0 >> 1) + hx;
    int i00 = (2 * hy + 1) * SW + (2 * hx + 1);
    float4 a00 = L4s[i00], a01 = L4s[i00 + 1], a10 = L4s[i00 + SW], a11 = L4s[i00 + SW + 1];
    float sl = 0.f;
    sl += a00.x + a01.x + a10.x + a11.x;
    sl += a00.y + a01.y + a10.y + a11.y;
    sl += a00.z + a01.z + a10.z + a11.z;
    float sr = 0.f;
    int yy2 = y0 + 2 * hy, xx2 = x0 + 2 * hx;
    #pragma unroll
    for (int c = 0; c < 3; c++) {
      const float* rp = rb + (size_t)(c * H + yy2) * W + xx2;
      sr += rp[0] + rp[1] + rp[W] + rp[W + 1];
    }
    size_t ho = (size_t)b * (H2 * W2) + (size_t)y2g * W2 + x2g;
    lg[ho] = sl * (1.f / 12.f);
    rg[ho] = sr * (1.f / 12.f);
  }

  float v[6];
  #pragma unroll
  for (int s = 0; s < 6; s++) v[s] = 0.f;

  {
    const int tx = tid & 31, ty = tid >> 5;
    const int x = x0 + tx, y = y0 + ty;
    const size_t gidx = (size_t)b * H * W + (size_t)y * W + x;
    const int ci = (ty + 1) * SW + (tx + 1);

    float sl[3] = {0,0,0}, sw[3] = {0,0,0}, sl2[3] = {0,0,0},
          sw2[3] = {0,0,0}, slw[3] = {0,0,0};
    float4 cl4, cw4, rl4, dl4;
    #pragma unroll
    for (int dy = -1; dy <= 1; dy++) {
      #pragma unroll
      for (int dx = -1; dx <= 1; dx++) {
        int ni = ci + dy * SW + dx;
        float4 a = L4s[ni];
        float4 wv = W4s[ni];
        sl[0] += a.x;  sl2[0] += a.x * a.x;  sw[0] += wv.x;  sw2[0] += wv.x * wv.x;  slw[0] += a.x * wv.x;
        sl[1] += a.y;  sl2[1] += a.y * a.y;  sw[1] += wv.y;  sw2[1] += wv.y * wv.y;  slw[1] += a.y * wv.y;
        sl[2] += a.z;  sl2[2] += a.z * a.z;  sw[2] += wv.z;  sw2[2] += wv.z * wv.z;  slw[2] += a.z * wv.z;
        if (dy == 0 && dx == 0) { cl4 = a; cw4 = wv; }
        if (dy == 0 && dx == 1) rl4 = a;
        if (dy == 1 && dx == 0) dl4 = a;
      }
    }
    float ds = cl4.w;

    // ---- gt anchor ----
    {
      float g = gt[gidx];
      float trust = (g > 2.0f) ? conf[gidx] * occ[gidx] : 0.f;
      v[0] = trust * fabsf(ds - g);
      v[1] = trust;
    }

    // ---- photometric ----
    {
      float xs = (float)x - ds;
      bool valid = (xs > 0.f) && (xs < (float)(W - 1));
      float cl[3] = {cl4.x, cl4.y, cl4.z};
      float cw[3] = {cw4.x, cw4.y, cw4.z};
      float ssm = 0.f, l1m = 0.f;
      #pragma unroll
      for (int c = 0; c < 3; c++) {
        float mx = sl[c] * (1.f / 9.f), my = sw[c] * (1.f / 9.f);
        float sx = fmaxf(sl2[c] * (1.f / 9.f) - mx * mx, 0.f);
        float sy = fmaxf(sw2[c] * (1.f / 9.f) - my * my, 0.f);
        float sxy = slw[c] * (1.f / 9.f) - mx * my;
        float n  = (2.f * mx * my + 1e-4f) * (2.f * sxy + 9e-4f);
        float dd = (mx * mx + my * my + 1e-4f) * (sx + sy + 9e-4f);
        float ss = (1.f - n / dd) * 0.5f;
        ss = fminf(fmaxf(ss, 0.f), 1.f);
        ssm += ss;
        l1m += fabsf(cl[c] - cw[c]);
      }
      ssm *= (1.f / 3.f); l1m *= (1.f / 3.f);
      float err = 0.85f * ssm + 0.15f * l1m;
      if (valid) { v[2] = err; v[3] = 1.f; }
    }

    // ---- smoothness ----
    if (x < W - 1) {
      float ddx = fabsf(rl4.w - ds);
      float idx = fabsf(rl4.x - cl4.x) + fabsf(rl4.y - cl4.y) + fabsf(rl4.z - cl4.z);
      v[4] = ddx * __expf(-idx * (1.f / 3.f));
    }
    if (y < H - 1) {
      float ddy = fabsf(dl4.w - ds);
      float idy = fabsf(dl4.x - cl4.x) + fabsf(dl4.y - cl4.y) + fabsf(dl4.z - cl4.z);
      v[5] = ddy * __expf(-idy * (1.f / 3.f));
    }
  }

  __shared__ float sm[4][6];
  int wave = threadIdx.x >> 6, lane = threadIdx.x & 63;
  #pragma unroll
  for (int s = 0; s < 6; s++) {
    float r = waveSum(v[s]);
    if (lane == 0) sm[wave][s] = r;
  }
  __syncthreads();
  if (threadIdx.x < 6) {
    float t = sm[0][threadIdx.x] + sm[1][threadIdx.x] +
              sm[2][threadIdx.x] + sm[3][threadIdx.x];
    partialsA[(size_t)threadIdx.x * NBLK + blockIdx.x] = t;
  }
}

// ---------------- fused NCC disparity search, 4 d-groups (R12) --------------------
// grp g covers 12 d's: g0 [-24..-13], g1 [-12..-1], g2 [1..12], g3 [13..24].
// R12 = R11's (numerically verified) single-d pipeline with the register caches
// expressed as NAMED SCALARS and a fully STRAIGHT-LINE d-loop.
// R10/R11 post-mortem: float rgv[29]/lgc[18] living across the d-loop were
// demoted to scratch by the compiler even with all-literal indices
// (VGPR pinned at 64 < the 128 cap; WRITE_SIZE 432 MB). Named scalars are SSA
// values after mem2reg — no alloca exists to demote. CH pass = 18-parameter
// macro CH_BODY invoked 12x with shifted register-name windows; arithmetic
// sequence matches R11 exactly. Small constant-indexed arrays (bnum/lmS/...)
// are R7-proven safe and kept.
// LDS 8848 floats = 35392 B -> 4 blocks/CU (layout identical to R11):
//   @0:    LGs 26x74 (dead after LH) overlaid by RMS float2[16][76] (2432)
//   @2432: RGs 26x88 (85 logical cols, padded for float4 preload)
//   @4720: POOL 3328 (LH pair / VR pair / CH ping-pong, stride 64)
//   @8048: P1 16x25 | @8448: P2
constexpr int RGST = 88;   // padded RGs row stride (352 B, 16B-aligned rows)

// CH pass body: pure register FMAs from named lgc (l0..l17) x an 18-wide
// named-rgv window, then two b128 stores. Association matches R11:
// s starts at 0 and accumulates term by term; window updates add
// (l_{j+10}*w_{j+10} - l_{j-1}*w_{j-1}) as a single += expression.
#define CH_BODY(dstp, w0,w1,w2,w3,w4,w5,w6,w7,w8,w9,w10,w11,w12,w13,w14,w15,w16,w17) \
  do {                                                                         \
    if (hr < 26) {                                                             \
      float s_ = 0.f;                                                          \
      s_ += l0*w0;  s_ += l1*w1;  s_ += l2*w2;  s_ += l3*w3;                   \
      s_ += l4*w4;  s_ += l5*w5;  s_ += l6*w6;  s_ += l7*w7;                   \
      s_ += l8*w8;  s_ += l9*w9;  s_ += l10*w10;                               \
      float c0_ = s_;                                                          \
      s_ += l11*w11 - l0*w0;   float c1_ = s_;                                 \
      s_ += l12*w12 - l1*w1;   float c2_ = s_;                                 \
      s_ += l13*w13 - l2*w2;   float c3_ = s_;                                 \
      s_ += l14*w14 - l3*w3;   float c4_ = s_;                                 \
      s_ += l15*w15 - l4*w4;   float c5_ = s_;                                 \
      s_ += l16*w16 - l5*w5;   float c6_ = s_;                                 \
      s_ += l17*w17 - l6*w6;   float c7_ = s_;                                 \
      *(float4*)&(dstp)[chbase]     = make_float4(c0_, c1_, c2_, c3_);         \
      *(float4*)&(dstp)[chbase + 4] = make_float4(c4_, c5_, c6_, c7_);         \
    }                                                                          \
  } while (0)

// Vertical phase for iteration IT (LITERAL), sub-row K (LITERAL): identical
// arithmetic/order to R11's inner loop.
#define VPK(IT, K)                                                             \
  do {                                                                         \
    if ((K) > 0) a_ += CHr[vbase + ((K) + 10) * 64] - CHr[vbase + ((K) - 1) * 64]; \
    float cs_ = a_;                                                            \
    float2 ms_ = *(const float2*)&RMS[rmsb + (K) * 152 + 2 * (IT)];            \
    float rm_ = ms_.x, rstd_ = ms_.y;                                          \
    if (edgeL) {                                                               \
      float rs_ = rm_ * 121.f;                                                 \
      float r2_ = (rstd_ * rstd_ + rm_ * rm_) * 121.f;                         \
      int ai_, bI_;                                                            \
      if (headL) { ai_ = max(gx - 5 + d_, 0); bI_ = d_; }                      \
      else       { ai_ = 24 + d_; bI_ = min(gx + 5 + d_, 479) - 455; }         \
      rs_ -= P1[(vys + (K)) * 25 + bI_] - P1[(vys + (K)) * 25 + ai_];          \
      r2_ -= P2[(vys + (K)) * 25 + bI_] - P2[(vys + (K)) * 25 + ai_];          \
      rm_ = rs_ * (1.f / 121.f);                                               \
      rstd_ = sqrtf(fmaxf(r2_ * (1.f / 121.f) - rm_ * rm_, 1e-8f));            \
    }                                                                          \
    float num_ = __builtin_fmaf(-lmS[(K)], rm_, cs_);                          \
    float den_ = __builtin_fmaf(lsS[(K)], rstd_, 1.21e-6f);                    \
    if (num_ * bden[(K)] > bnum[(K)] * den_) {                                 \
      bnum[(K)] = num_; bden[(K)] = den_; bdd[(K)] = (float)d_;                \
    }                                                                          \
  } while (0)

#define VPH(IT)                                                                \
  do {                                                                         \
    float* CHr = POOL + (((IT) & 1) ? 1664 : 0);                               \
    const int d_ = dmin + (IT);                                                \
    float a_ = 0.f;                                                            \
    a_ += CHr[vbase];        a_ += CHr[vbase + 64];  a_ += CHr[vbase + 128];   \
    a_ += CHr[vbase + 192];  a_ += CHr[vbase + 256]; a_ += CHr[vbase + 320];   \
    a_ += CHr[vbase + 384];  a_ += CHr[vbase + 448]; a_ += CHr[vbase + 512];   \
    a_ += CHr[vbase + 576];  a_ += CHr[vbase + 640];                           \
    VPK(IT, 0); VPK(IT, 1); VPK(IT, 2); VPK(IT, 3);                            \
  } while (0)

__global__ __launch_bounds__(256, 4) void k_ncc(const float* __restrict__ lg,
                                                const float* __restrict__ rg,
                                                float* __restrict__ bcA,
                                                float* __restrict__ bdA) {
  const int z = blockIdx.z;
  const int b = z >> 2, grp = z & 3;
  const int dmin = (grp == 0) ? -24 : ((grp == 1) ? -12 : ((grp == 2) ? 1 : 13));
  const int x0 = blockIdx.x * 64;
  const int y0 = blockIdx.y * 16;
  const int tid = threadIdx.x;

  __shared__ __align__(16) float SM[8848];
  float* LGs = SM;             // 26 x 74
  float* RMS = SM;             // float2[16][76] row-major (overlays dead LGs)
  float* RGs = SM + 2432;      // 26 x 88 (logical 85 cols)
  float* POOL = SM + 4720;     // 3328
  float* P1 = SM + 8048;       // 16 x 25
  float* P2 = SM + 8448;

  const float* lgb = lg + (size_t)b * (H2 * W2);
  const float* rgb = rg + (size_t)b * (H2 * W2);

  for (int e = tid; e < 26 * 74; e += 256) {
    int r = e / 74, c = e % 74;
    int gy = y0 - 5 + r, gxx = x0 - 5 + c;
    LGs[e] = (gy >= 0 && gy < H2 && gxx >= 0 && gxx < W2) ? lgb[gy * W2 + gxx] : 0.f;
  }
  const int col0RG = x0 - 5 + dmin;
  for (int e = tid; e < 26 * 85; e += 256) {
    int r = e / 85, c = e % 85;
    int gy = y0 - 5 + r, gxx = col0RG + c;
    RGs[r * RGST + c] = (gy >= 0 && gy < H2 && gxx >= 0 && gxx < W2) ? rgb[gy * W2 + gxx] : 0.f;
  }
  __syncthreads();

  // ---- LH pass (horizontal 11-sums of lg, lg^2) + named register caches ----
  const int hg = tid & 7, hr = tid >> 3;
  const int chbase = hr * 64 + 8 * hg;
  // named lgc scalars
  float l0, l1, l2, l3, l4, l5, l6, l7, l8, l9, l10, l11, l12, l13, l14, l15, l16, l17;
  // named rgv scalars (29-wide window this thread needs across all 12 d's)
  float r0, r1, r2, r3, r4, r5, r6, r7, r8, r9, r10, r11, r12, r13, r14,
        r15, r16, r17, r18, r19, r20, r21, r22, r23, r24, r25, r26, r27, r28;
  float* LH1 = POOL;           // 26 x 64
  float* LH2 = POOL + 1664;
  if (hr < 26) {
    const float* lp = &LGs[hr * 74 + 8 * hg];
    l0 = lp[0];  l1 = lp[1];  l2 = lp[2];  l3 = lp[3];  l4 = lp[4];  l5 = lp[5];
    l6 = lp[6];  l7 = lp[7];  l8 = lp[8];  l9 = lp[9];  l10 = lp[10]; l11 = lp[11];
    l12 = lp[12]; l13 = lp[13]; l14 = lp[14]; l15 = lp[15]; l16 = lp[16]; l17 = lp[17];
    const float* rp = &RGs[hr * RGST + 8 * hg];
    float4 qa = *(const float4*)(rp);
    float4 qb = *(const float4*)(rp + 4);
    float4 qc = *(const float4*)(rp + 8);
    float4 qd = *(const float4*)(rp + 12);
    float4 qe = *(const float4*)(rp + 16);
    float4 qf = *(const float4*)(rp + 20);
    float4 qg = *(const float4*)(rp + 24);
    r0 = qa.x;  r1 = qa.y;  r2 = qa.z;  r3 = qa.w;
    r4 = qb.x;  r5 = qb.y;  r6 = qb.z;  r7 = qb.w;
    r8 = qc.x;  r9 = qc.y;  r10 = qc.z; r11 = qc.w;
    r12 = qd.x; r13 = qd.y; r14 = qd.z; r15 = qd.w;
    r16 = qe.x; r17 = qe.y; r18 = qe.z; r19 = qe.w;
    r20 = qf.x; r21 = qf.y; r22 = qf.z; r23 = qf.w;
    r24 = qg.x; r25 = qg.y; r26 = qg.z; r27 = qg.w;
    r28 = rp[28];

    float s1 = 0.f, s2 = 0.f;
    s1 += l0;  s2 += l0 * l0;   s1 += l1;  s2 += l1 * l1;
    s1 += l2;  s2 += l2 * l2;   s1 += l3;  s2 += l3 * l3;
    s1 += l4;  s2 += l4 * l4;   s1 += l5;  s2 += l5 * l5;
    s1 += l6;  s2 += l6 * l6;   s1 += l7;  s2 += l7 * l7;
    s1 += l8;  s2 += l8 * l8;   s1 += l9;  s2 += l9 * l9;
    s1 += l10; s2 += l10 * l10;
    float w1_0 = s1, w2_0 = s2;
    s1 += l11 - l0;  s2 += l11 * l11 - l0 * l0;  float w1_1 = s1, w2_1 = s2;
    s1 += l12 - l1;  s2 += l12 * l12 - l1 * l1;  float w1_2 = s1, w2_2 = s2;
    s1 += l13 - l2;  s2 += l13 * l13 - l2 * l2;  float w1_3 = s1, w2_3 = s2;
    s1 += l14 - l3;  s2 += l14 * l14 - l3 * l3;  float w1_4 = s1, w2_4 = s2;
    s1 += l15 - l4;  s2 += l15 * l15 - l4 * l4;  float w1_5 = s1, w2_5 = s2;
    s1 += l16 - l5;  s2 += l16 * l16 - l5 * l5;  float w1_6 = s1, w2_6 = s2;
    s1 += l17 - l6;  s2 += l17 * l17 - l6 * l6;  float w1_7 = s1, w2_7 = s2;
    *(float4*)&LH1[chbase]     = make_float4(w1_0, w1_1, w1_2, w1_3);
    *(float4*)&LH1[chbase + 4] = make_float4(w1_4, w1_5, w1_6, w1_7);
    *(float4*)&LH2[chbase]     = make_float4(w2_0, w2_1, w2_2, w2_3);
    *(float4*)&LH2[chbase + 4] = make_float4(w2_4, w2_5, w2_6, w2_7);
  }
  // ---- border column sums (head: global cols 0..23; tail: 456..479) ----
  const bool headT = (grp >= 2) && (x0 == 0);
  const bool tailT = (grp < 2) && (x0 == 448);
  if (headT || tailT) {
    int gcol0 = headT ? 0 : 456;
    for (int e = tid; e < 16 * 24; e += 256) {
      int y = e / 24, i = e % 24;
      int lc = gcol0 + i - col0RG;
      float v1 = 0.f, v2 = 0.f;
      if (lc >= 0 && lc < 85) {
        #pragma unroll
        for (int dy = 0; dy < 11; dy++) {
          float v = RGs[(y + dy) * RGST + lc];
          v1 += v; v2 += v * v;
        }
      }
      P1[y * 25 + i + 1] = v1;
      P2[y * 25 + i + 1] = v2;
    }
  }
  __syncthreads();

  if ((headT || tailT) && tid < 16) {
    int y = tid;
    float s1 = 0.f, s2 = 0.f;
    P1[y * 25] = 0.f; P2[y * 25] = 0.f;
    for (int k = 0; k < 24; k++) {
      s1 += P1[y * 25 + k + 1]; P1[y * 25 + k + 1] = s1;
      s2 += P2[y * 25 + k + 1]; P2[y * 25 + k + 1] = s2;
    }
  }
  const int vx = tid & 63;
  const int vys = (tid >> 6) * 4;
  const int vbase = vys * 64 + vx;
  const int rmsb = vys * 152 + 2 * vx;
  float lmS[4], lsS[4];   // 121-scaled left mean / std
  {
    float s1 = 0.f, s2 = 0.f;
    #pragma unroll
    for (int dy = 0; dy < 11; dy++) { s1 += LH1[(vys + dy) * 64 + vx]; s2 += LH2[(vys + dy) * 64 + vx]; }
    #pragma unroll
    for (int k = 0; k < 4; k++) {
      if (k) {
        s1 += LH1[(vys + k + 10) * 64 + vx] - LH1[(vys + k - 1) * 64 + vx];
        s2 += LH2[(vys + k + 10) * 64 + vx] - LH2[(vys + k - 1) * 64 + vx];
      }
      float m = s1 * (1.f / 121.f);
      float s = sqrtf(fmaxf(s2 * (1.f / 121.f) - m * m, 1e-8f));
      lmS[k] = m * 121.f;
      lsS[k] = s * 121.f;
    }
  }
  __syncthreads();

  // ---- VR pass: vertical 11-sums of rg, rg^2 (POOL, overwrites LH) ----
  float* VR1 = POOL;           // 16 x 85
  float* VR2 = POOL + 1360;
  if (tid < 170) {
    int c = tid % 85;
    int rr0 = (tid / 85) * 8;
    float s1 = 0.f, s2 = 0.f;
    #pragma unroll
    for (int dy = 0; dy < 11; dy++) {
      float v = RGs[(rr0 + dy) * RGST + c];
      s1 += v; s2 += v * v;
    }
    VR1[rr0 * 85 + c] = s1; VR2[rr0 * 85 + c] = s2;
    #pragma unroll
    for (int k = 1; k < 8; k++) {
      float vin  = RGs[(rr0 + k + 10) * RGST + c];
      float vout = RGs[(rr0 + k - 1) * RGST + c];
      s1 += vin - vout;
      s2 += vin * vin - vout * vout;
      VR1[(rr0 + k) * 85 + c] = s1; VR2[(rr0 + k) * 85 + c] = s2;
    }
  }
  __syncthreads();

  // ---- RV pass fused with moment transform -> RMS float2 (rm, rstd) ----
  {
    int r = tid >> 4, seg = tid & 15;
    int c0 = seg * 5;
    if (c0 < 75) {
      float s1 = 0.f, s2 = 0.f;
      #pragma unroll
      for (int m = 0; m < 11; m++) { s1 += VR1[r * 85 + c0 + m]; s2 += VR2[r * 85 + c0 + m]; }
      #pragma unroll
      for (int j = 0; j < 5; j++) {
        if (j) {
          s1 += VR1[r * 85 + c0 + j + 10] - VR1[r * 85 + c0 + j - 1];
          s2 += VR2[r * 85 + c0 + j + 10] - VR2[r * 85 + c0 + j - 1];
        }
        float rm = s1 * (1.f / 121.f);
        float rstd = sqrtf(fmaxf(s2 * (1.f / 121.f) - rm * rm, 1e-8f));
        *(float2*)&RMS[r * 152 + 2 * (c0 + j)] = make_float2(rm, rstd);
      }
    }
  }
  __syncthreads();

  // ---- d loop: 12 straight-line single-d iterations, CH ping-pong ----
  const int gx = x0 + vx;
  const bool headL = (grp >= 2) && (gx < 5);
  const bool tailL = (grp < 2) && (gx > 474);
  const bool edgeL = headL || tailL;
  float bnum[4], bden[4], bdd[4];
  #pragma unroll
  for (int k = 0; k < 4; k++) { bnum[k] = -1.f; bden[k] = 1.f; bdd[k] = 0.f; }

  float* BUF0 = POOL;           // even-d CH buffer
  float* BUF1 = POOL + 1664;    // odd-d CH buffer

  // prologue: CH(0) into BUF0 (POOL free: VR dead after RMS pass)
  CH_BODY(BUF0, r0,r1,r2,r3,r4,r5,r6,r7,r8,r9,r10,r11,r12,r13,r14,r15,r16,r17);
  __syncthreads();

  // IT=0: prefetch CH(1)->BUF1, consume BUF0
  CH_BODY(BUF1, r1,r2,r3,r4,r5,r6,r7,r8,r9,r10,r11,r12,r13,r14,r15,r16,r17,r18);
  VPH(0);
  __syncthreads();
  // IT=1
  CH_BODY(BUF0, r2,r3,r4,r5,r6,r7,r8,r9,r10,r11,r12,r13,r14,r15,r16,r17,r18,r19);
  VPH(1);
  __syncthreads();
  // IT=2
  CH_BODY(BUF1, r3,r4,r5,r6,r7,r8,r9,r10,r11,r12,r13,r14,r15,r16,r17,r18,r19,r20);
  VPH(2);
  __syncthreads();
  // IT=3
  CH_BODY(BUF0, r4,r5,r6,r7,r8,r9,r10,r11,r12,r13,r14,r15,r16,r17,r18,r19,r20,r21);
  VPH(3);
  __syncthreads();
  // IT=4
  CH_BODY(BUF1, r5,r6,r7,r8,r9,r10,r11,r12,r13,r14,r15,r16,r17,r18,r19,r20,r21,r22);
  VPH(4);
  __syncthreads();
  // IT=5
  CH_BODY(BUF0, r6,r7,r8,r9,r10,r11,r12,r13,r14,r15,r16,r17,r18,r19,r20,r21,r22,r23);
  VPH(5);
  __syncthreads();
  // IT=6
  CH_BODY(BUF1, r7,r8,r9,r10,r11,r12,r13,r14,r15,r16,r17,r18,r19,r20,r21,r22,r23,r24);
  VPH(6);
  __syncthreads();
  // IT=7
  CH_BODY(BUF0, r8,r9,r10,r11,r12,r13,r14,r15,r16,r17,r18,r19,r20,r21,r22,r23,r24,r25);
  VPH(7);
  __syncthreads();
  // IT=8
  CH_BODY(BUF1, r9,r10,r11,r12,r13,r14,r15,r16,r17,r18,r19,r20,r21,r22,r23,r24,r25,r26);
  VPH(8);
  __syncthreads();
  // IT=9
  CH_BODY(BUF0, r10,r11,r12,r13,r14,r15,r16,r17,r18,r19,r20,r21,r22,r23,r24,r25,r26,r27);
  VPH(9);
  __syncthreads();
  // IT=10
  CH_BODY(BUF1, r11,r12,r13,r14,r15,r16,r17,r18,r19,r20,r21,r22,r23,r24,r25,r26,r27,r28);
  VPH(10);
  __syncthreads();
  // IT=11: no prefetch
  VPH(11);

  if (gx < W2) {
    float* bcp = bcA + (size_t)grp * NH + (size_t)b * (H2 * W2);
    float* bdp = bdA + (size_t)grp * NH + (size_t)b * (H2 * W2);
    #pragma unroll
    for (int k = 0; k < 4; k++) {
      size_t o = (size_t)(y0 + vys + k) * W2 + gx;
      bcp[o] = bnum[k] / bden[k];
      bdp[o] = bdd[k];
    }
  }
}

// ------- sign/magnitude: merge 4 d-groups (ascending, strict >), 4 preds each -------
__global__ __launch_bounds__(256) void k_sgm(const float* __restrict__ pred,
                                             const float* __restrict__ bcA,
                                             const float* __restrict__ bdA,
                                             float* __restrict__ partialsB) {
  int tid = blockIdx.x * 256 + threadIdx.x;
  float v6 = 0.f, v7 = 0.f, v8 = 0.f;
  if (tid < NH) {
    int b = tid / (H2 * W2);
    int rem = tid % (H2 * W2);
    int y2 = rem / W2, x2 = rem % W2;
    float bcv = bcA[tid];
    float bdv = bdA[tid];
    #pragma unroll
    for (int g = 1; g < 4; g++) {
      float c = bcA[(size_t)g * NH + tid];
      if (c > bcv) { bcv = c; bdv = bdA[(size_t)g * NH + tid]; }
    }
    if (bcv > 0.3f) {
      float nd = bdv * 2.f;
      float sgn = (nd > 0.f) ? 1.f : ((nd < 0.f) ? -1.f : 0.f);
      const float* pb = pred + (size_t)b * H * W;
      #pragma unroll
      for (int dy = 0; dy < 2; dy++) {
        #pragma unroll
        for (int dx = 0; dx < 2; dx++) {
          float p = pb[(size_t)(2 * y2 + dy) * W + 2 * x2 + dx];
          v6 += fmaxf(-p * sgn, 0.f);
          v7 += bcv * fabsf(p - nd);
        }
      }
      v8 = 4.f;
    }
  }
  __shared__ float sm[4][3];
  int wave = threadIdx.x >> 6, lane = threadIdx.x & 63;
  float r;
  r = waveSum(v6); if (lane == 0) sm[wave][0] = r;
  r = waveSum(v7); if (lane == 0) sm[wave][1] = r;
  r = waveSum(v8); if (lane == 0) sm[wave][2] = r;
  __syncthreads();
  if (threadIdx.x < 3) {
    float t = sm[0][threadIdx.x] + sm[1][threadIdx.x] +
              sm[2][threadIdx.x] + sm[3][threadIdx.x];
    partialsB[(size_t)threadIdx.x * NBLK2 + blockIdx.x] = t;
  }
}

// ---------------- final reduction + scalar composition (1024 threads) ----------------
__global__ __launch_bounds__(1024) void k_final(const float* __restrict__ PA,
                                                const float* __restrict__ PB,
                                                float* __restrict__ out) {
  __shared__ float red[9][16];
  int lane = threadIdx.x & 63, wave = threadIdx.x >> 6;
  #pragma unroll
  for (int s = 0; s < 6; s++) {
    float l = 0.f;
    for (int i = threadIdx.x; i < NBLK; i += 1024) l += PA[(size_t)s * NBLK + i];
    l = waveSum(l);
    if (lane == 0) red[s][wave] = l;
  }
  #pragma unroll
  for (int s = 0; s < 3; s++) {
    float l = 0.f;
    for (int i = threadIdx.x; i < NBLK2; i += 1024) l += PB[(size_t)s * NBLK2 + i];
    l = waveSum(l);
    if (lane == 0) red[6 + s][wave] = l;
  }
  __syncthreads();
  if (threadIdx.x == 0) {
    float a[9];
    #pragma unroll
    for (int s = 0; s < 9; s++) {
      float t = 0.f;
      #pragma unroll
      for (int q = 0; q < 16; q++) t += red[s][q];
      a[s] = t;
    }
    float gtl = a[0] / fmaxf(a[1], 1.f);
    float ph  = a[2] / fmaxf(a[3], 1.f);
    float n   = fmaxf(a[8], 1.f);
    float smv = 0.3f * (a[6] / n) + 0.7f * (a[7] / n);
    float smo = a[4] * (1.f / ((float)B * H * (W - 1)))
              + a[5] * (1.f / ((float)B * (H - 1) * W));
    out[0] = gtl + ph + 0.5f * smv + 0.1f * smo;
  }
}

extern "C" void kernel_launch(void* const* d_in, const int* in_sizes, int n_in,
                              void* d_out, int out_size, void* d_ws, size_t ws_size,
                              hipStream_t stream) {
  const float* pred  = (const float*)d_in[0];
  const float* gt    = (const float*)d_in[1];
  const float* conf  = (const float*)d_in[2];
  const float* occ   = (const float*)d_in[3];
  const float* left  = (const float*)d_in[4];
  const float* right = (const float*)d_in[5];
  float* out = (float*)d_out;

  float* ws = (float*)d_ws;
  float* lg  = ws;
  float* rg  = ws + (size_t)NH;
  float* bcA = ws + 2 * (size_t)NH;                  // 4 * NH
  float* bdA = ws + 6 * (size_t)NH;                  // 4 * NH
  float* partialsA = ws + 10 * (size_t)NH;           // 6 * NBLK
  float* partialsB = partialsA + 6 * (size_t)NBLK;   // 3 * NBLK2

  k_pix<<<NBLK, 256, 0, stream>>>(pred, gt, conf, occ, left, right,
                                  lg, rg, partialsA);

  dim3 nccGrid(8, 17, 16);   // x-tiles, y-tiles, batch*4 d-groups
  k_ncc<<<nccGrid, 256, 0, stream>>>(lg, rg, bcA, bdA);

  k_sgm<<<NBLK2, 256, 0, stream>>>(pred, bcA, bdA, partialsB);

  k_final<<<1, 1024, 0, stream>>>(partialsA, partialsB, out);
}

// Round 4
// 232.832 us; speedup vs baseline: 1.9036x; 1.0484x over previous
//
#include <hip/hip_runtime.h>
#include <hip/hip_bf16.h>

// Problem constants (match reference setup_inputs / hyperparams)
constexpr int B  = 4;
constexpr int H  = 544;
constexpr int W  = 960;
constexpr int H2 = 272;   // half-res
constexpr int W2 = 480;
constexpr int NH = B * H2 * W2;     // 522240
constexpr int NF = B * H * W;       // 2088960

// pixel kernel tiling: 32x8 outputs per block, halo 1 -> 34x10 staged
constexpr int TPW = 32, TPH = 8;
constexpr int SW = TPW + 2, SH = TPH + 2;      // 34 x 10
constexpr int NSTAGE = SW * SH;                // 340
constexpr int GX = W / TPW;                    // 30
constexpr int GY = H / TPH;                    // 68
constexpr int NBLK  = GX * GY * B;             // 8160 (k_pix blocks)
constexpr int NBLK2 = (NH + 255) / 256;        // 2040 (k_sgm blocks)

__device__ inline float waveSum(float v) {
  #pragma unroll
  for (int off = 32; off > 0; off >>= 1) v += __shfl_down(v, off, 64);
  return v;
}

// ------- fused pixel kernel: gt + photometric + smoothness + lg/rg downsample -------
__global__ __launch_bounds__(256) void k_pix(const float* __restrict__ pred,
                                             const float* __restrict__ gt,
                                             const float* __restrict__ conf,
                                             const float* __restrict__ occ,
                                             const float* __restrict__ left,
                                             const float* __restrict__ right,
                                             float* __restrict__ lg,
                                             float* __restrict__ rg,
                                             float* __restrict__ partialsA) {
  const int bx = blockIdx.x % GX;
  const int by = (blockIdx.x / GX) % GY;
  const int b  = blockIdx.x / (GX * GY);
  const int x0 = bx * TPW, y0 = by * TPH;
  const int tid = threadIdx.x;

  const float* dispb = pred + (size_t)b * H * W;
  const float* lb = left  + (size_t)b * 3 * H * W;
  const float* rb = right + (size_t)b * 3 * H * W;

  __shared__ float4 L4s[NSTAGE];   // (lv0, lv1, lv2, disp); zeros if OOB
  __shared__ float4 W4s[NSTAGE];   // (wv0, wv1, wv2, 0);    zeros if OOB

  for (int e = tid; e < NSTAGE; e += 256) {
    int r = e / SW, c = e % SW;
    int yy = y0 - 1 + r, xx = x0 - 1 + c;
    float4 l4 = make_float4(0.f, 0.f, 0.f, 0.f);
    float4 w4 = make_float4(0.f, 0.f, 0.f, 0.f);
    if (yy >= 0 && yy < H && xx >= 0 && xx < W) {
      float dv = dispb[yy * W + xx];
      float xsv = (float)xx - dv;
      float xc = fminf(fmaxf(xsv, 0.f), (float)(W - 1));
      float x0f = floorf(xc);
      float w = xc - x0f;
      int x0i = (int)x0f;
      int x1i = min(x0i + 1, W - 1);
      const float* l0 = lb + (size_t)yy * W;
      const float* r0 = rb + (size_t)yy * W;
      l4.x = l0[xx];
      l4.y = l0[(size_t)H * W + xx];
      l4.z = l0[2 * (size_t)H * W + xx];
      l4.w = dv;
      w4.x = r0[x0i] * (1.f - w) + r0[x1i] * w;
      w4.y = r0[(size_t)H * W + x0i] * (1.f - w) + r0[(size_t)H * W + x1i] * w;
      w4.z = r0[2 * (size_t)H * W + x0i] * (1.f - w) + r0[2 * (size_t)H * W + x1i] * w;
    }
    L4s[e] = l4; W4s[e] = w4;
  }
  __syncthreads();

  // ---- lg/rg emission (threads 0..63): 16x4 half-res pixels of this tile ----
  if (tid < 64) {
    int hx = tid & 15, hy = tid >> 4;
    int y2g = (y0 >> 1) + hy, x2g = (x0 >> 1) + hx;
    int i00 = (2 * hy + 1) * SW + (2 * hx + 1);
    float4 a00 = L4s[i00], a01 = L4s[i00 + 1], a10 = L4s[i00 + SW], a11 = L4s[i00 + SW + 1];
    float sl = 0.f;
    sl += a00.x + a01.x + a10.x + a11.x;
    sl += a00.y + a01.y + a10.y + a11.y;
    sl += a00.z + a01.z + a10.z + a11.z;
    float sr = 0.f;
    int yy2 = y0 + 2 * hy, xx2 = x0 + 2 * hx;
    #pragma unroll
    for (int c = 0; c < 3; c++) {
      const float* rp = rb + (size_t)(c * H + yy2) * W + xx2;
      sr += rp[0] + rp[1] + rp[W] + rp[W + 1];
    }
    size_t ho = (size_t)b * (H2 * W2) + (size_t)y2g * W2 + x2g;
    lg[ho] = sl * (1.f / 12.f);
    rg[ho] = sr * (1.f / 12.f);
  }

  float v[6];
  #pragma unroll
  for (int s = 0; s < 6; s++) v[s] = 0.f;

  {
    const int tx = tid & 31, ty = tid >> 5;
    const int x = x0 + tx, y = y0 + ty;
    const size_t gidx = (size_t)b * H * W + (size_t)y * W + x;
    const int ci = (ty + 1) * SW + (tx + 1);

    float sl[3] = {0,0,0}, sw[3] = {0,0,0}, sl2[3] = {0,0,0},
          sw2[3] = {0,0,0}, slw[3] = {0,0,0};
    float4 cl4, cw4, rl4, dl4;
    #pragma unroll
    for (int dy = -1; dy <= 1; dy++) {
      #pragma unroll
      for (int dx = -1; dx <= 1; dx++) {
        int ni = ci + dy * SW + dx;
        float4 a = L4s[ni];
        float4 wv = W4s[ni];
        sl[0] += a.x;  sl2[0] += a.x * a.x;  sw[0] += wv.x;  sw2[0] += wv.x * wv.x;  slw[0] += a.x * wv.x;
        sl[1] += a.y;  sl2[1] += a.y * a.y;  sw[1] += wv.y;  sw2[1] += wv.y * wv.y;  slw[1] += a.y * wv.y;
        sl[2] += a.z;  sl2[2] += a.z * a.z;  sw[2] += wv.z;  sw2[2] += wv.z * wv.z;  slw[2] += a.z * wv.z;
        if (dy == 0 && dx == 0) { cl4 = a; cw4 = wv; }
        if (dy == 0 && dx == 1) rl4 = a;
        if (dy == 1 && dx == 0) dl4 = a;
      }
    }
    float ds = cl4.w;

    // ---- gt anchor ----
    {
      float g = gt[gidx];
      float trust = (g > 2.0f) ? conf[gidx] * occ[gidx] : 0.f;
      v[0] = trust * fabsf(ds - g);
      v[1] = trust;
    }

    // ---- photometric ----
    {
      float xs = (float)x - ds;
      bool valid = (xs > 0.f) && (xs < (float)(W - 1));
      float cl[3] = {cl4.x, cl4.y, cl4.z};
      float cw[3] = {cw4.x, cw4.y, cw4.z};
      float ssm = 0.f, l1m = 0.f;
      #pragma unroll
      for (int c = 0; c < 3; c++) {
        float mx = sl[c] * (1.f / 9.f), my = sw[c] * (1.f / 9.f);
        float sx = fmaxf(sl2[c] * (1.f / 9.f) - mx * mx, 0.f);
        float sy = fmaxf(sw2[c] * (1.f / 9.f) - my * my, 0.f);
        float sxy = slw[c] * (1.f / 9.f) - mx * my;
        float n  = (2.f * mx * my + 1e-4f) * (2.f * sxy + 9e-4f);
        float dd = (mx * mx + my * my + 1e-4f) * (sx + sy + 9e-4f);
        float ss = (1.f - n / dd) * 0.5f;
        ss = fminf(fmaxf(ss, 0.f), 1.f);
        ssm += ss;
        l1m += fabsf(cl[c] - cw[c]);
      }
      ssm *= (1.f / 3.f); l1m *= (1.f / 3.f);
      float err = 0.85f * ssm + 0.15f * l1m;
      if (valid) { v[2] = err; v[3] = 1.f; }
    }

    // ---- smoothness ----
    if (x < W - 1) {
      float ddx = fabsf(rl4.w - ds);
      float idx = fabsf(rl4.x - cl4.x) + fabsf(rl4.y - cl4.y) + fabsf(rl4.z - cl4.z);
      v[4] = ddx * __expf(-idx * (1.f / 3.f));
    }
    if (y < H - 1) {
      float ddy = fabsf(dl4.w - ds);
      float idy = fabsf(dl4.x - cl4.x) + fabsf(dl4.y - cl4.y) + fabsf(dl4.z - cl4.z);
      v[5] = ddy * __expf(-idy * (1.f / 3.f));
    }
  }

  __shared__ float sm[4][6];
  int wave = threadIdx.x >> 6, lane = threadIdx.x & 63;
  #pragma unroll
  for (int s = 0; s < 6; s++) {
    float r = waveSum(v[s]);
    if (lane == 0) sm[wave][s] = r;
  }
  __syncthreads();
  if (threadIdx.x < 6) {
    float t = sm[0][threadIdx.x] + sm[1][threadIdx.x] +
              sm[2][threadIdx.x] + sm[3][threadIdx.x];
    partialsA[(size_t)threadIdx.x * NBLK + blockIdx.x] = t;
  }
}

// ---------------- fused NCC disparity search, 4 d-groups (R13) --------------------
// grp g covers 12 d's: g0 [-24..-13], g1 [-12..-1], g2 [1..12], g3 [13..24].
// R13 = R7's verified pair-loop structure (zero scratch, VGPR ~60) with the
// y-tile shrunk 16 -> 8 for occupancy.
// R10-R12 post-mortem: the RA pins this kernel at 64 VGPR and spills any
// register cache living across the d-loop (lambda / switch-literal / named
// scalars all spilled; WRITE_SIZE 432->64 MB arc, no speedup). Accept the
// 64-VGPR budget. Counters say latency-bound (VALUBusy 34%, LDS ~14% of BW,
// HBM 3%, conflicts 4%) with occupancy capped by LDS at 4 blocks/CU -> the
// lever is footprint: 18 staged rows instead of 26.
// LDS 5568 floats = 22272 B -> 7 blocks/CU (28 waves/CU, +75% concurrency)
// for +38% halo overhead. Grid y: 34 (= 272/8 exact).
//   @0:    LGs 18x74 = 1332 (dead after LH) overlaid by RMS float2[8][76] = 1216
//   @1332: RGs 18x85 = 1530
//   @2864: POOL 2304 (LH pair 18x64 / VR pair 8x85 / CH pair, stride 64)
//   @5168: P1 8x25 | @5368: P2 8x25
// (POOL at 2864 keeps float4 accesses 16B-aligned.)
__global__ __launch_bounds__(256) void k_ncc(const float* __restrict__ lg,
                                             const float* __restrict__ rg,
                                             float* __restrict__ bcA,
                                             float* __restrict__ bdA) {
  const int z = blockIdx.z;
  const int b = z >> 2, grp = z & 3;
  const int dmin = (grp == 0) ? -24 : ((grp == 1) ? -12 : ((grp == 2) ? 1 : 13));
  const int x0 = blockIdx.x * 64;
  const int y0 = blockIdx.y * 8;
  const int tid = threadIdx.x;

  __shared__ __align__(16) float SM[5568];
  float* LGs = SM;             // 18 x 74
  float* RMS = SM;             // float2[8][76] row-major (overlays dead LGs)
  float* RGs = SM + 1332;      // 18 x 85
  float* POOL = SM + 2864;     // 2304
  float* P1 = SM + 5168;       // 8 x 25
  float* P2 = SM + 5368;

  const float* lgb = lg + (size_t)b * (H2 * W2);
  const float* rgb = rg + (size_t)b * (H2 * W2);

  for (int e = tid; e < 18 * 74; e += 256) {
    int r = e / 74, c = e % 74;
    int gy = y0 - 5 + r, gxx = x0 - 5 + c;
    LGs[e] = (gy >= 0 && gy < H2 && gxx >= 0 && gxx < W2) ? lgb[gy * W2 + gxx] : 0.f;
  }
  const int col0RG = x0 - 5 + dmin;
  for (int e = tid; e < 18 * 85; e += 256) {
    int r = e / 85, c = e % 85;
    int gy = y0 - 5 + r, gxx = col0RG + c;
    RGs[e] = (gy >= 0 && gy < H2 && gxx >= 0 && gxx < W2) ? rgb[gy * W2 + gxx] : 0.f;
  }
  __syncthreads();

  // ---- LH pass (horizontal 11-sums of lg, lg^2) + lgc register cache ----
  const int hg = tid & 7, hr = tid >> 3;
  float lgc[18];
  float* LH1 = POOL;           // 18 x 64
  float* LH2 = POOL + 1152;
  if (hr < 18) {
    #pragma unroll
    for (int k = 0; k < 18; k++) lgc[k] = LGs[hr * 74 + 8 * hg + k];
    float w1[8], w2[8];
    float s1 = 0.f, s2 = 0.f;
    #pragma unroll
    for (int k = 0; k < 11; k++) { s1 += lgc[k]; s2 += lgc[k] * lgc[k]; }
    w1[0] = s1; w2[0] = s2;
    #pragma unroll
    for (int j = 1; j < 8; j++) {
      s1 += lgc[j + 10] - lgc[j - 1];
      s2 += lgc[j + 10] * lgc[j + 10] - lgc[j - 1] * lgc[j - 1];
      w1[j] = s1; w2[j] = s2;
    }
    *(float4*)&LH1[hr * 64 + 8 * hg]     = make_float4(w1[0], w1[1], w1[2], w1[3]);
    *(float4*)&LH1[hr * 64 + 8 * hg + 4] = make_float4(w1[4], w1[5], w1[6], w1[7]);
    *(float4*)&LH2[hr * 64 + 8 * hg]     = make_float4(w2[0], w2[1], w2[2], w2[3]);
    *(float4*)&LH2[hr * 64 + 8 * hg + 4] = make_float4(w2[4], w2[5], w2[6], w2[7]);
  }
  // ---- border column sums (head: global cols 0..23; tail: 456..479) ----
  const bool headT = (grp >= 2) && (x0 == 0);
  const bool tailT = (grp < 2) && (x0 == 448);
  if (headT || tailT) {
    int gcol0 = headT ? 0 : 456;
    for (int e = tid; e < 8 * 24; e += 256) {
      int y = e / 24, i = e % 24;
      int lc = gcol0 + i - col0RG;
      float v1 = 0.f, v2 = 0.f;
      if (lc >= 0 && lc < 85) {
        #pragma unroll
        for (int dy = 0; dy < 11; dy++) {
          float v = RGs[(y + dy) * 85 + lc];
          v1 += v; v2 += v * v;
        }
      }
      P1[y * 25 + i + 1] = v1;
      P2[y * 25 + i + 1] = v2;
    }
  }
  __syncthreads();

  if ((headT || tailT) && tid < 8) {
    int y = tid;
    float s1 = 0.f, s2 = 0.f;
    P1[y * 25] = 0.f; P2[y * 25] = 0.f;
    for (int k = 0; k < 24; k++) {
      s1 += P1[y * 25 + k + 1]; P1[y * 25 + k + 1] = s1;
      s2 += P2[y * 25 + k + 1]; P2[y * 25 + k + 1] = s2;
    }
  }
  const int vx = tid & 63;
  const int vys = (tid >> 6) * 2;    // 4 waves x 2 rows = 8 output rows
  float lmS[2], lsS[2];   // 121-scaled left mean / std
  {
    float s1 = 0.f, s2 = 0.f;
    #pragma unroll
    for (int dy = 0; dy < 11; dy++) { s1 += LH1[(vys + dy) * 64 + vx]; s2 += LH2[(vys + dy) * 64 + vx]; }
    #pragma unroll
    for (int k = 0; k < 2; k++) {
      if (k) {
        s1 += LH1[(vys + k + 10) * 64 + vx] - LH1[(vys + k - 1) * 64 + vx];
        s2 += LH2[(vys + k + 10) * 64 + vx] - LH2[(vys + k - 1) * 64 + vx];
      }
      float m = s1 * (1.f / 121.f);
      float s = sqrtf(fmaxf(s2 * (1.f / 121.f) - m * m, 1e-8f));
      lmS[k] = m * 121.f;
      lsS[k] = s * 121.f;
    }
  }
  __syncthreads();

  // ---- VR pass: vertical 11-sums of rg, rg^2 (POOL, overwrites LH) ----
  float* VR1 = POOL;           // 8 x 85
  float* VR2 = POOL + 680;
  if (tid < 170) {
    int c = tid % 85;
    int rr0 = (tid / 85) * 4;
    float s1 = 0.f, s2 = 0.f;
    #pragma unroll
    for (int dy = 0; dy < 11; dy++) {
      float v = RGs[(rr0 + dy) * 85 + c];
      s1 += v; s2 += v * v;
    }
    VR1[rr0 * 85 + c] = s1; VR2[rr0 * 85 + c] = s2;
    #pragma unroll
    for (int k = 1; k < 4; k++) {
      float vin  = RGs[(rr0 + k + 10) * 85 + c];
      float vout = RGs[(rr0 + k - 1) * 85 + c];
      s1 += vin - vout;
      s2 += vin * vin - vout * vout;
      VR1[(rr0 + k) * 85 + c] = s1; VR2[(rr0 + k) * 85 + c] = s2;
    }
  }
  __syncthreads();

  // ---- RV pass fused with moment transform -> RMS float2 (rm, rstd) ----
  {
    int r = tid >> 5, seg = tid & 31;
    int c0 = seg * 3;
    if (c0 < 75) {
      float s1 = 0.f, s2 = 0.f;
      #pragma unroll
      for (int m = 0; m < 11; m++) { s1 += VR1[r * 85 + c0 + m]; s2 += VR2[r * 85 + c0 + m]; }
      #pragma unroll
      for (int j = 0; j < 3; j++) {
        if (j) {
          s1 += VR1[r * 85 + c0 + j + 10] - VR1[r * 85 + c0 + j - 1];
          s2 += VR2[r * 85 + c0 + j + 10] - VR2[r * 85 + c0 + j - 1];
        }
        if (c0 + j < 75) {
          float rm = s1 * (1.f / 121.f);
          float rstd = sqrtf(fmaxf(s2 * (1.f / 121.f) - rm * rm, 1e-8f));
          *(float2*)&RMS[r * 152 + 2 * (c0 + j)] = make_float2(rm, rstd);
        }
      }
    }
  }
  __syncthreads();

  // ---- d loop: 6 pairs (d, d+1) within this group's 12 d's ----
  float* CH0 = POOL;           // 18 x 64
  float* CH1 = POOL + 1152;
  const int gx = x0 + vx;
  const bool headL = (grp >= 2) && (gx < 5);
  const bool tailL = (grp < 2) && (gx > 474);
  const bool edgeL = headL || tailL;
  float bnum[2], bden[2], bdd[2];
  #pragma unroll
  for (int k = 0; k < 2; k++) { bnum[k] = -1.f; bden[k] = 1.f; bdd[k] = 0.f; }

  for (int it = 0; it < 6; ++it) {
    const int d0 = dmin + 2 * it;
    if (hr < 18) {
      const int c0 = 8 * hg + 2 * it;
      float rgv[19];
      #pragma unroll
      for (int j = 0; j < 19; j++) rgv[j] = RGs[hr * 85 + c0 + j];
      float ca[8], cb[8];
      float sa = 0.f, sb = 0.f;
      #pragma unroll
      for (int k = 0; k < 11; k++) { sa += lgc[k] * rgv[k]; sb += lgc[k] * rgv[k + 1]; }
      ca[0] = sa; cb[0] = sb;
      #pragma unroll
      for (int j = 1; j < 8; j++) {
        sa += lgc[j + 10] * rgv[j + 10] - lgc[j - 1] * rgv[j - 1];
        sb += lgc[j + 10] * rgv[j + 11] - lgc[j - 1] * rgv[j];
        ca[j] = sa; cb[j] = sb;
      }
      *(float4*)&CH0[hr * 64 + 8 * hg]     = make_float4(ca[0], ca[1], ca[2], ca[3]);
      *(float4*)&CH0[hr * 64 + 8 * hg + 4] = make_float4(ca[4], ca[5], ca[6], ca[7]);
      *(float4*)&CH1[hr * 64 + 8 * hg]     = make_float4(cb[0], cb[1], cb[2], cb[3]);
      *(float4*)&CH1[hr * 64 + 8 * hg + 4] = make_float4(cb[4], cb[5], cb[6], cb[7]);
    }
    __syncthreads();
    {
      float a0 = 0.f, a1 = 0.f;
      #pragma unroll
      for (int dy = 0; dy < 11; dy++) { a0 += CH0[(vys + dy) * 64 + vx]; a1 += CH1[(vys + dy) * 64 + vx]; }
      #pragma unroll
      for (int k = 0; k < 2; k++) {
        if (k) {
          a0 += CH0[(vys + k + 10) * 64 + vx] - CH0[(vys + k - 1) * 64 + vx];
          a1 += CH1[(vys + k + 10) * 64 + vx] - CH1[(vys + k - 1) * 64 + vx];
        }
        #pragma unroll
        for (int h = 0; h < 2; h++) {
          int d = d0 + h;
          float cs = h ? a1 : a0;            // raw 121-sum of lg*rg_shift
          int rvi = vx + 2 * it + h;
          float2 ms = *(const float2*)&RMS[(vys + k) * 152 + 2 * rvi];
          float rm = ms.x, rstd = ms.y;
          if (edgeL) {
            float rs = rm * 121.f;
            float r2 = (rstd * rstd + rm * rm) * 121.f;
            int a, bI;
            if (headL) { a = max(gx - 5 + d, 0); bI = d; }
            else       { a = 24 + d; bI = min(gx + 5 + d, 479) - 455; }
            rs -= P1[(vys + k) * 25 + bI] - P1[(vys + k) * 25 + a];
            r2 -= P2[(vys + k) * 25 + bI] - P2[(vys + k) * 25 + a];
            rm = rs * (1.f / 121.f);
            rstd = sqrtf(fmaxf(r2 * (1.f / 121.f) - rm * rm, 1e-8f));
          }
          float num = __builtin_fmaf(-lmS[k], rm, cs);
          float den = __builtin_fmaf(lsS[k], rstd, 1.21e-6f);
          if (num * bden[k] > bnum[k] * den) { bnum[k] = num; bden[k] = den; bdd[k] = (float)d; }
        }
      }
    }
    __syncthreads();
  }

  if (gx < W2) {
    float* bcp = bcA + (size_t)grp * NH + (size_t)b * (H2 * W2);
    float* bdp = bdA + (size_t)grp * NH + (size_t)b * (H2 * W2);
    #pragma unroll
    for (int k = 0; k < 2; k++) {
      size_t o = (size_t)(y0 + vys + k) * W2 + gx;
      bcp[o] = bnum[k] / bden[k];
      bdp[o] = bdd[k];
    }
  }
}

// ------- sign/magnitude: merge 4 d-groups (ascending, strict >), 4 preds each -------
__global__ __launch_bounds__(256) void k_sgm(const float* __restrict__ pred,
                                             const float* __restrict__ bcA,
                                             const float* __restrict__ bdA,
                                             float* __restrict__ partialsB) {
  int tid = blockIdx.x * 256 + threadIdx.x;
  float v6 = 0.f, v7 = 0.f, v8 = 0.f;
  if (tid < NH) {
    int b = tid / (H2 * W2);
    int rem = tid % (H2 * W2);
    int y2 = rem / W2, x2 = rem % W2;
    float bcv = bcA[tid];
    float bdv = bdA[tid];
    #pragma unroll
    for (int g = 1; g < 4; g++) {
      float c = bcA[(size_t)g * NH + tid];
      if (c > bcv) { bcv = c; bdv = bdA[(size_t)g * NH + tid]; }
    }
    if (bcv > 0.3f) {
      float nd = bdv * 2.f;
      float sgn = (nd > 0.f) ? 1.f : ((nd < 0.f) ? -1.f : 0.f);
      const float* pb = pred + (size_t)b * H * W;
      #pragma unroll
      for (int dy = 0; dy < 2; dy++) {
        #pragma unroll
        for (int dx = 0; dx < 2; dx++) {
          float p = pb[(size_t)(2 * y2 + dy) * W + 2 * x2 + dx];
          v6 += fmaxf(-p * sgn, 0.f);
          v7 += bcv * fabsf(p - nd);
        }
      }
      v8 = 4.f;
    }
  }
  __shared__ float sm[4][3];
  int wave = threadIdx.x >> 6, lane = threadIdx.x & 63;
  float r;
  r = waveSum(v6); if (lane == 0) sm[wave][0] = r;
  r = waveSum(v7); if (lane == 0) sm[wave][1] = r;
  r = waveSum(v8); if (lane == 0) sm[wave][2] = r;
  __syncthreads();
  if (threadIdx.x < 3) {
    float t = sm[0][threadIdx.x] + sm[1][threadIdx.x] +
              sm[2][threadIdx.x] + sm[3][threadIdx.x];
    partialsB[(size_t)threadIdx.x * NBLK2 + blockIdx.x] = t;
  }
}

// ---------------- final reduction + scalar composition (1024 threads) ----------------
__global__ __launch_bounds__(1024) void k_final(const float* __restrict__ PA,
                                                const float* __restrict__ PB,
                                                float* __restrict__ out) {
  __shared__ float red[9][16];
  int lane = threadIdx.x & 63, wave = threadIdx.x >> 6;
  #pragma unroll
  for (int s = 0; s < 6; s++) {
    float l = 0.f;
    for (int i = threadIdx.x; i < NBLK; i += 1024) l += PA[(size_t)s * NBLK + i];
    l = waveSum(l);
    if (lane == 0) red[s][wave] = l;
  }
  #pragma unroll
  for (int s = 0; s < 3; s++) {
    float l = 0.f;
    for (int i = threadIdx.x; i < NBLK2; i += 1024) l += PB[(size_t)s * NBLK2 + i];
    l = waveSum(l);
    if (lane == 0) red[6 + s][wave] = l;
  }
  __syncthreads();
  if (threadIdx.x == 0) {
    float a[9];
    #pragma unroll
    for (int s = 0; s < 9; s++) {
      float t = 0.f;
      #pragma unroll
      for (int q = 0; q < 16; q++) t += red[s][q];
      a[s] = t;
    }
    float gtl = a[0] / fmaxf(a[1], 1.f);
    float ph  = a[2] / fmaxf(a[3], 1.f);
    float n   = fmaxf(a[8], 1.f);
    float smv = 0.3f * (a[6] / n) + 0.7f * (a[7] / n);
    float smo = a[4] * (1.f / ((float)B * H * (W - 1)))
              + a[5] * (1.f / ((float)B * (H - 1) * W));
    out[0] = gtl + ph + 0.5f * smv + 0.1f * smo;
  }
}

extern "C" void kernel_launch(void* const* d_in, const int* in_sizes, int n_in,
                              void* d_out, int out_size, void* d_ws, size_t ws_size,
                              hipStream_t stream) {
  const float* pred  = (const float*)d_in[0];
  const float* gt    = (const float*)d_in[1];
  const float* conf  = (const float*)d_in[2];
  const float* occ   = (const float*)d_in[3];
  const float* left  = (const float*)d_in[4];
  const float* right = (const float*)d_in[5];
  float* out = (float*)d_out;

  float* ws = (float*)d_ws;
  float* lg  = ws;
  float* rg  = ws + (size_t)NH;
  float* bcA = ws + 2 * (size_t)NH;                  // 4 * NH
  float* bdA = ws + 6 * (size_t)NH;                  // 4 * NH
  float* partialsA = ws + 10 * (size_t)NH;           // 6 * NBLK
  float* partialsB = partialsA + 6 * (size_t)NBLK;   // 3 * NBLK2

  k_pix<<<NBLK, 256, 0, stream>>>(pred, gt, conf, occ, left, right,
                                  lg, rg, partialsA);

  dim3 nccGrid(8, 34, 16);   // x-tiles, y-tiles (272/8), batch*4 d-groups
  k_ncc<<<nccGrid, 256, 0, stream>>>(lg, rg, bcA, bdA);

  k_sgm<<<NBLK2, 256, 0, stream>>>(pred, bcA, bdA, partialsB);

  k_final<<<1, 1024, 0, stream>>>(partialsA, partialsB, out);
}